// Round 5
// baseline (113.392 us; speedup 1.0000x reference)
//
#include <hip/hip_runtime.h>

#define EPS 1e-5f

typedef _Float16 half8 __attribute__((ext_vector_type(8)));
typedef _Float16 half4 __attribute__((ext_vector_type(4)));
typedef float f32x16 __attribute__((ext_vector_type(16)));
typedef float f32x4v __attribute__((ext_vector_type(4)));

// ---------------------------------------------------------------------------
// pre_kernel: blocks 0..255 = hxhy via MFMA (w1 consumed directly, alpha/bias
// folded in epilogue); blocks 256..319 = weight prep (BN-fold w2/w3, cast w4).
// ---------------------------------------------------------------------------
__global__ __launch_bounds__(256)
void pre_kernel(
    const float* __restrict__ x, const float* __restrict__ y,
    const float* __restrict__ w1, const float* __restrict__ b1,
    const float* __restrict__ g1, const float* __restrict__ be1,
    const float* __restrict__ m1, const float* __restrict__ v1,
    const float* __restrict__ w2, const float* __restrict__ b2,
    const float* __restrict__ g2, const float* __restrict__ be2,
    const float* __restrict__ m2, const float* __restrict__ v2,
    const float* __restrict__ w3, const float* __restrict__ b3,
    const float* __restrict__ g3, const float* __restrict__ be3,
    const float* __restrict__ m3, const float* __restrict__ v3,
    const float* __restrict__ w4,
    _Float16* __restrict__ hxh, _Float16* __restrict__ hyh,
    _Float16* __restrict__ w2h, _Float16* __restrict__ w3h,
    _Float16* __restrict__ w4h,
    float* __restrict__ b2f, float* __restrict__ b3f)
{
    const int t = threadIdx.x;

    if (blockIdx.x >= 256) {
        // ---------------- prep part ----------------
        int tid = (blockIdx.x - 256) * 256 + t;
        const int nth = 64 * 256;
        for (int idx = tid; idx < 256 * 512; idx += nth) {
            int n = idx >> 9;
            float a = g2[n] * rsqrtf(v2[n] + EPS);
            w2h[idx] = (_Float16)(a * w2[idx]);
        }
        for (int idx = tid; idx < 128 * 256; idx += nth) {
            int n = idx >> 8;
            float a = g3[n] * rsqrtf(v3[n] + EPS);
            w3h[idx] = (_Float16)(a * w3[idx]);
        }
        for (int idx = tid; idx < 64 * 128; idx += nth) {
            w4h[idx] = (_Float16)w4[idx];
        }
        if (tid < 256) {
            float a = g2[tid] * rsqrtf(v2[tid] + EPS);
            b2f[tid] = a * b2[tid] + be2[tid] - m2[tid] * a;
        } else if (tid < 384) {
            int n = tid - 256;
            float a = g3[n] * rsqrtf(v3[n] + EPS);
            b3f[n] = a * b3[n] + be3[n] - m3[n] * a;
        }
        return;
    }

    // ---------------- hxhy part ----------------
    // bid: rg = 32-row group (32), ng = 128-col group (4), which = x/y (2)
    const int rg = blockIdx.x & 31;
    const int ng = (blockIdx.x >> 5) & 3;
    const int which = blockIdx.x >> 7;

    constexpr int LDA = 136;  // 272 B row stride
    __shared__ _Float16 sh[32 * 136 + 128 * 136] __attribute__((aligned(16)));
    _Float16* xa = sh;                 // [32][136]
    _Float16* wb = sh + 32 * 136;      // [128][136]

    const int rowbase = rg * 32;
    const float* src = which ? y : x;

    // stage A: 32 rows x 128 f32 -> f16
#pragma unroll
    for (int p = 0; p < 4; ++p) {
        int c = p * 256 + t;               // 0..1023 float4-chunks
        int r = c >> 5, fo = (c & 31) * 4;
        f32x4v v = *(const f32x4v*)(src + (size_t)(rowbase + r) * 128 + fo);
        half4 h; h[0] = (_Float16)v[0]; h[1] = (_Float16)v[1];
        h[2] = (_Float16)v[2]; h[3] = (_Float16)v[3];
        *(half4*)(xa + r * LDA + fo) = h;
    }
    // stage B: 128 n-rows x 128 k f32 -> f16 (w1 row-major, k-offset by which)
#pragma unroll
    for (int p = 0; p < 16; ++p) {
        int c = p * 256 + t;               // 0..4095
        int n = c >> 5, fo = (c & 31) * 4;
        f32x4v v = *(const f32x4v*)(w1 + (size_t)(ng * 128 + n) * 256 + which * 128 + fo);
        half4 h; h[0] = (_Float16)v[0]; h[1] = (_Float16)v[1];
        h[2] = (_Float16)v[2]; h[3] = (_Float16)v[3];
        *(half4*)(wb + n * LDA + fo) = h;
    }
    __syncthreads();

    const int wid = t >> 6;
    const int l = t & 63;
    const int l31 = l & 31, lh = l >> 5;

    f32x16 acc = (f32x16)0.f;
#pragma unroll
    for (int kc = 0; kc < 8; ++kc) {
        half8 af = *(const half8*)(xa + l31 * LDA + kc * 16 + lh * 8);
        half8 bf = *(const half8*)(wb + (wid * 32 + l31) * LDA + kc * 16 + lh * 8);
        acc = __builtin_amdgcn_mfma_f32_32x32x16_f16(af, bf, acc, 0, 0, 0);
    }

    const int n = ng * 128 + wid * 32 + l31;
    float alpha = g1[n] * rsqrtf(v1[n] + EPS);
    float bias = which ? 0.f : (alpha * b1[n] + be1[n] - m1[n] * alpha);
    _Float16* dst = which ? hyh : hxh;
#pragma unroll
    for (int r = 0; r < 16; ++r) {
        int m = (r & 3) + 8 * (r >> 2) + 4 * lh;
        dst[(size_t)(rowbase + m) * 512 + n] = (_Float16)(alpha * acc[r] + bias);
    }
}

// ---------------------------------------------------------------------------
// fused: one block per (b,i); b = bid&7 (XCD-affine: all i of one b share an
// XCD's L2 -> hy/w2 L2-resident). M=128 (all j), 512->256->128->64 MLP.
// L2 phase: A-fragments assembled IN REGISTERS from global hy + LDS-broadcast
// hx (rank-1 structure) -- no a1 staging, no a1 fragment LDS reads. w2 staged
// in LDS K=32 double-buffered with quad-spread XOR swizzle (0 conflicts).
// 512 threads = 8 waves. LDS 71168 B -> 2 blocks/CU.
// ---------------------------------------------------------------------------
__global__ __launch_bounds__(512, 4)
void fused_kernel(
    const _Float16* __restrict__ hxh, const _Float16* __restrict__ hyh,
    const _Float16* __restrict__ w2h, const _Float16* __restrict__ w3h,
    const _Float16* __restrict__ w4h,
    const float* __restrict__ b2f, const float* __restrict__ b3f,
    const float* __restrict__ b4,
    float* __restrict__ out)
{
    constexpr int LD2 = 264;  // a2 row stride (halves), 528 B (proven 0-conflict)
    constexpr int LD3 = 136;  // a3 row stride (halves), 272 B
    constexpr int LDE = 68;   // es row stride (f32), 272 B

    __shared__ char smem[3584 + 67584] __attribute__((aligned(16)));
    _Float16* hxs = (_Float16*)smem;             // [512] f16   1024 B
    float* spart  = (float*)(smem + 1024);       // [8][64]     2048 B
    float* ss     = (float*)(smem + 3072);       // [64]         256 B
    char* R1 = smem + 3584;
    _Float16* w2t0 = (_Float16*)R1;              // [256][32] swz 16384 B
    _Float16* w2t1 = (_Float16*)(R1 + 16384);    // [256][32] swz 16384 B
    _Float16* a2  = (_Float16*)R1;               // [128][264] 67584 B (after L2)
    _Float16* a3  = (_Float16*)R1;               // [128][136] (after L3)
    float*    es  = (float*)R1;                  // [128][68]  (after L4)

    const int b = blockIdx.x & 7;                // XCD-affine mapping
    const int i = blockIdx.x >> 3;
    const int t = threadIdx.x;
    const int wid = t >> 6;
    const int l   = t & 63;
    const int l31 = l & 31;
    const int lh  = l >> 5;

    if (t < 64)
        *(half8*)(hxs + t * 8) = *(const half8*)(hxh + (size_t)(b * 128 + i) * 512 + t * 8);
    __syncthreads();

    const int wm = wid >> 2, wn = wid & 3;       // 2 x 4 wave grid (L2/L3)
    const size_t hyb = (size_t)b * 65536;

    // ---------------- layer 2: [128x512] @ [256x512]^T ----------------
    f32x16 acc2[2][2];
#pragma unroll
    for (int mt = 0; mt < 2; ++mt)
#pragma unroll
        for (int nt = 0; nt < 2; ++nt) acc2[mt][nt] = (f32x16)0.f;

    // w2 staging map: thread -> row n = t>>1, chunks kc2, kc2+1 (16B each)
    const int sn = t >> 1, kc2 = (t & 1) * 2;
    const int fW = (sn >> 1) & 3;                // write-side swizzle
    const int fB = (l31 >> 1) & 3;               // read-side swizzle

    // A-fragment source rows (hy): per-thread fixed pointers
    const _Float16* hyr0 = hyh + hyb + (size_t)(wm * 64 + l31) * 512 + lh * 8;
    const _Float16* hyr1 = hyr0 + 32 * 512;

    half8 rw0, rw1;                              // w2 staging regs
    half8 raA[2][2], raB[2][2];                  // A prefetch [kk][mt]

    auto LOADW = [&](int kt) {
        const _Float16* wp = w2h + (size_t)sn * 512 + kt * 32 + kc2 * 8;
        rw0 = *(const half8*)wp;
        rw1 = *(const half8*)(wp + 8);
    };
    auto WRITEW = [&](_Float16* W) {
        *(half8*)(W + sn * 32 + ((kc2 ^ fW) << 3))       = rw0;
        *(half8*)(W + sn * 32 + (((kc2 + 1) ^ fW) << 3)) = rw1;
    };
    auto LOADA = [&](half8 (&ra)[2][2], int kt) {
#pragma unroll
        for (int kk = 0; kk < 2; ++kk) {
            ra[kk][0] = *(const half8*)(hyr0 + kt * 32 + kk * 16);
            ra[kk][1] = *(const half8*)(hyr1 + kt * 32 + kk * 16);
        }
    };
    auto MFMASTEP = [&](const _Float16* W, half8 (&ra)[2][2], int kt) {
#pragma unroll
        for (int kk = 0; kk < 2; ++kk) {
            half8 rx = *(const half8*)(hxs + kt * 32 + kk * 16 + lh * 8);
            half8 af[2], bf[2];
#pragma unroll
            for (int mt = 0; mt < 2; ++mt) {
                half8 s = ra[kk][mt] + rx;
#pragma unroll
                for (int c = 0; c < 8; ++c)
                    af[mt][c] = s[c] > (_Float16)0.f ? s[c] : (_Float16)0.f;
            }
#pragma unroll
            for (int nt = 0; nt < 2; ++nt)
                bf[nt] = *(const half8*)(W + (wn * 64 + nt * 32 + l31) * 32 +
                                         (((kk * 2 + lh) ^ fB) << 3));
            acc2[0][0] = __builtin_amdgcn_mfma_f32_32x32x16_f16(af[0], bf[0], acc2[0][0], 0, 0, 0);
            acc2[1][0] = __builtin_amdgcn_mfma_f32_32x32x16_f16(af[1], bf[0], acc2[1][0], 0, 0, 0);
            acc2[0][1] = __builtin_amdgcn_mfma_f32_32x32x16_f16(af[0], bf[1], acc2[0][1], 0, 0, 0);
            acc2[1][1] = __builtin_amdgcn_mfma_f32_32x32x16_f16(af[1], bf[1], acc2[1][1], 0, 0, 0);
        }
    };

    LOADA(raA, 0);
    LOADW(0);
    WRITEW(w2t0);
    __syncthreads();

    for (int kt = 0; kt < 16; kt += 2) {
        // even step: compute on w2t0/raA, stage kt+1 into w2t1/raB
        LOADW(kt + 1);
        LOADA(raB, kt + 1);
        MFMASTEP(w2t0, raA, kt);
        WRITEW(w2t1);
        __syncthreads();
        // odd step: compute on w2t1/raB, stage kt+2 into w2t0/raA
        if (kt + 2 < 16) {
            LOADW(kt + 2);
            LOADA(raA, kt + 2);
        }
        MFMASTEP(w2t1, raB, kt + 1);
        if (kt + 2 < 16) WRITEW(w2t0);
        __syncthreads();
    }

    // epilogue -> a2 (fp16, relu); aliases staging bufs (dead after last sync)
    {
        float bb0 = b2f[wn * 64 + l31];
        float bb1 = b2f[wn * 64 + 32 + l31];
#pragma unroll
        for (int mt = 0; mt < 2; ++mt)
#pragma unroll
            for (int r = 0; r < 16; ++r) {
                int m = wm * 64 + mt * 32 + (r & 3) + 8 * (r >> 2) + 4 * lh;
                a2[m * LD2 + wn * 64 + l31]      = (_Float16)fmaxf(acc2[mt][0][r] + bb0, 0.f);
                a2[m * LD2 + wn * 64 + 32 + l31] = (_Float16)fmaxf(acc2[mt][1][r] + bb1, 0.f);
            }
    }
    __syncthreads();

    // ---------------- layer 3: [128x256] @ [128x256]^T, B direct from L2 ----
    f32x16 acc3[2];
    acc3[0] = (f32x16)0.f; acc3[1] = (f32x16)0.f;
#pragma unroll 8
    for (int kc = 0; kc < 16; ++kc) {
        half8 bfr = *(const half8*)(w3h + (size_t)(wn * 32 + l31) * 256 + kc * 16 + lh * 8);
        half8 af0 = *(const half8*)(a2 + (wm * 64 + l31) * LD2 + kc * 16 + lh * 8);
        half8 af1 = *(const half8*)(a2 + (wm * 64 + 32 + l31) * LD2 + kc * 16 + lh * 8);
        acc3[0] = __builtin_amdgcn_mfma_f32_32x32x16_f16(af0, bfr, acc3[0], 0, 0, 0);
        acc3[1] = __builtin_amdgcn_mfma_f32_32x32x16_f16(af1, bfr, acc3[1], 0, 0, 0);
    }
    __syncthreads();
    {
        float b3v = b3f[wn * 32 + l31];
#pragma unroll
        for (int mt = 0; mt < 2; ++mt)
#pragma unroll
            for (int r = 0; r < 16; ++r) {
                int m = wm * 64 + mt * 32 + (r & 3) + 8 * (r >> 2) + 4 * lh;
                a3[m * LD3 + wn * 32 + l31] = (_Float16)fmaxf(acc3[mt][r] + b3v, 0.f);
            }
    }
    __syncthreads();

    // ---------------- layer 4: [128x128] @ [64x128]^T, regrid 4x2 ----------
    const int wm4 = wid >> 1, wn4 = wid & 1;
    f32x16 acc4 = (f32x16)0.f;
#pragma unroll
    for (int kc = 0; kc < 8; ++kc) {
        half8 afr = *(const half8*)(a3 + (wm4 * 32 + l31) * LD3 + kc * 16 + lh * 8);
        half8 bfr = *(const half8*)(w4h + (size_t)(wn4 * 32 + l31) * 128 + kc * 16 + lh * 8);
        acc4 = __builtin_amdgcn_mfma_f32_32x32x16_f16(afr, bfr, acc4, 0, 0, 0);
    }
    __syncthreads();  // a3 reads done before es overwrites it
    {
        float b4v = b4[wn4 * 32 + l31];
#pragma unroll
        for (int r = 0; r < 16; ++r) {
            int m = wm4 * 32 + (r & 3) + 8 * (r >> 2) + 4 * lh;
            es[m * LDE + wn4 * 32 + l31] = acc4[r] + b4v;
        }
    }
    __syncthreads();

    // ---------------- s = sum_j e ; out[j] = sum_k e[j][k]*s[k] ------------
    {
        float sv = 0.f;
#pragma unroll
        for (int jj = 0; jj < 16; ++jj) sv += es[(wid + jj * 8) * LDE + l];
        spart[wid * 64 + l] = sv;
    }
    __syncthreads();
    if (t < 64) {
        float s2 = 0.f;
#pragma unroll
        for (int r = 0; r < 8; ++r) s2 += spart[r * 64 + t];
        ss[t] = s2;
    }
    __syncthreads();
    {
        const int j = t >> 2, q = t & 3;
        float p = 0.f;
#pragma unroll
        for (int c = 0; c < 16; ++c) {
            int k = q + 4 * c;               // k-interleaved: 2 lanes/bank
            p += es[j * LDE + k] * ss[k];
        }
        p += __shfl_xor(p, 1);
        p += __shfl_xor(p, 2);
        if (q == 0) out[(size_t)(b * 128 + i) * 128 + j] = p;
    }
}

// ---------------------------------------------------------------------------
extern "C" void kernel_launch(void* const* d_in, const int* in_sizes, int n_in,
                              void* d_out, int out_size, void* d_ws, size_t ws_size,
                              hipStream_t stream)
{
    (void)in_sizes; (void)n_in; (void)out_size; (void)ws_size;

    const float* x   = (const float*)d_in[0];
    const float* y   = (const float*)d_in[1];
    const float* w1  = (const float*)d_in[2];
    const float* b1  = (const float*)d_in[3];
    const float* g1  = (const float*)d_in[4];
    const float* be1 = (const float*)d_in[5];
    const float* m1  = (const float*)d_in[6];
    const float* v1  = (const float*)d_in[7];
    const float* w2  = (const float*)d_in[8];
    const float* b2  = (const float*)d_in[9];
    const float* g2  = (const float*)d_in[10];
    const float* be2 = (const float*)d_in[11];
    const float* m2  = (const float*)d_in[12];
    const float* v2  = (const float*)d_in[13];
    const float* w3  = (const float*)d_in[14];
    const float* b3  = (const float*)d_in[15];
    const float* g3  = (const float*)d_in[16];
    const float* be3 = (const float*)d_in[17];
    const float* m3  = (const float*)d_in[18];
    const float* v3  = (const float*)d_in[19];
    const float* w4  = (const float*)d_in[20];
    const float* b4  = (const float*)d_in[21];
    float* out = (float*)d_out;

    // workspace layout (~2.44 MB)
    float* b2f = (float*)d_ws;                 // 256 f32
    float* b3f = b2f + 256;                    // 128 f32
    _Float16* w2h = (_Float16*)(b3f + 128);    // 131072 f16
    _Float16* w3h = w2h + 131072;              // 32768 f16
    _Float16* w4h = w3h + 32768;               // 8192 f16
    _Float16* hxh = w4h + 8192;                // 524288 f16
    _Float16* hyh = hxh + 524288;              // 524288 f16

    hipLaunchKernelGGL(pre_kernel, dim3(320), dim3(256), 0, stream,
                       x, y, w1, b1, g1, be1, m1, v1,
                       w2, b2, g2, be2, m2, v2,
                       w3, b3, g3, be3, m3, v3,
                       w4,
                       hxh, hyh, w2h, w3h, w4h, b2f, b3f);

    hipLaunchKernelGGL(fused_kernel, dim3(1024), dim3(512), 0, stream,
                       hxh, hyh, w2h, w3h, w4h, b2f, b3f, b4, out);
}

// Round 6
// 67.419 us; speedup vs baseline: 1.6819x; 1.6819x over previous
//
#include <hip/hip_runtime.h>

#define EPS 1e-5f

typedef _Float16 half8 __attribute__((ext_vector_type(8)));
typedef _Float16 half4 __attribute__((ext_vector_type(4)));
typedef float f32x16 __attribute__((ext_vector_type(16)));
typedef float f32x4v __attribute__((ext_vector_type(4)));

// Fragment layout for an [R x K] f16 matrix consumed as 32-row MFMA operand:
// element (row, k) -> ((row>>5)*(K/16) + (k>>4))*512 + ((k>>3)&1)*256 + (row&31)*8 + (k&7)
// so a wave's fragment load for (rowgroup rg, kslice ks) is base + (rg*(K/16)+ks)*512 + lane*8
// = 64 lanes x 16 B contiguous (perfectly coalesced).

// ---------------------------------------------------------------------------
// pre_kernel: blocks 0..255 = hxhy via MFMA (w1 consumed directly, alpha/bias
// folded in epilogue; hy written in fragment layout); blocks 256..319 =
// weight prep (BN-fold w2/w3, cast w4; all written in fragment layout).
// ---------------------------------------------------------------------------
__global__ __launch_bounds__(256)
void pre_kernel(
    const float* __restrict__ x, const float* __restrict__ y,
    const float* __restrict__ w1, const float* __restrict__ b1,
    const float* __restrict__ g1, const float* __restrict__ be1,
    const float* __restrict__ m1, const float* __restrict__ v1,
    const float* __restrict__ w2, const float* __restrict__ b2,
    const float* __restrict__ g2, const float* __restrict__ be2,
    const float* __restrict__ m2, const float* __restrict__ v2,
    const float* __restrict__ w3, const float* __restrict__ b3,
    const float* __restrict__ g3, const float* __restrict__ be3,
    const float* __restrict__ m3, const float* __restrict__ v3,
    const float* __restrict__ w4,
    _Float16* __restrict__ hxh, _Float16* __restrict__ hyh,
    _Float16* __restrict__ w2h, _Float16* __restrict__ w3h,
    _Float16* __restrict__ w4h,
    float* __restrict__ b2f, float* __restrict__ b3f)
{
    const int t = threadIdx.x;

    if (blockIdx.x >= 256) {
        // ---------------- prep part (fragment-scattered writes) ----------------
        int tid = (blockIdx.x - 256) * 256 + t;
        const int nth = 64 * 256;
        for (int idx = tid; idx < 256 * 512; idx += nth) {
            int n = idx >> 9, k = idx & 511;
            float a = g2[n] * rsqrtf(v2[n] + EPS);
            int addr = ((n >> 5) * 32 + (k >> 4)) * 512 + ((k >> 3) & 1) * 256 + (n & 31) * 8 + (k & 7);
            w2h[addr] = (_Float16)(a * w2[idx]);
        }
        for (int idx = tid; idx < 128 * 256; idx += nth) {
            int n = idx >> 8, k = idx & 255;
            float a = g3[n] * rsqrtf(v3[n] + EPS);
            int addr = ((n >> 5) * 16 + (k >> 4)) * 512 + ((k >> 3) & 1) * 256 + (n & 31) * 8 + (k & 7);
            w3h[addr] = (_Float16)(a * w3[idx]);
        }
        for (int idx = tid; idx < 64 * 128; idx += nth) {
            int n = idx >> 7, k = idx & 127;
            int addr = ((n >> 5) * 8 + (k >> 4)) * 512 + ((k >> 3) & 1) * 256 + (n & 31) * 8 + (k & 7);
            w4h[addr] = (_Float16)w4[idx];
        }
        if (tid < 256) {
            float a = g2[tid] * rsqrtf(v2[tid] + EPS);
            b2f[tid] = a * b2[tid] + be2[tid] - m2[tid] * a;
        } else if (tid < 384) {
            int n = tid - 256;
            float a = g3[n] * rsqrtf(v3[n] + EPS);
            b3f[n] = a * b3[n] + be3[n] - m3[n] * a;
        }
        return;
    }

    // ---------------- hxhy part ----------------
    // bid: rg = 32-row group (32), ng = 128-col group (4), which = x/y (2)
    const int rg = blockIdx.x & 31;
    const int ng = (blockIdx.x >> 5) & 3;
    const int which = blockIdx.x >> 7;

    constexpr int LDA = 136;  // 272 B row stride
    __shared__ _Float16 sh[32 * 136 + 128 * 136] __attribute__((aligned(16)));
    _Float16* xa = sh;                 // [32][136]
    _Float16* wb = sh + 32 * 136;      // [128][136]

    const int rowbase = rg * 32;
    const float* src = which ? y : x;

    // stage A: 32 rows x 128 f32 -> f16
#pragma unroll
    for (int p = 0; p < 4; ++p) {
        int c = p * 256 + t;               // 0..1023 float4-chunks
        int r = c >> 5, fo = (c & 31) * 4;
        f32x4v v = *(const f32x4v*)(src + (size_t)(rowbase + r) * 128 + fo);
        half4 h; h[0] = (_Float16)v[0]; h[1] = (_Float16)v[1];
        h[2] = (_Float16)v[2]; h[3] = (_Float16)v[3];
        *(half4*)(xa + r * LDA + fo) = h;
    }
    // stage B: 128 n-rows x 128 k f32 -> f16 (w1 row-major, k-offset by which)
#pragma unroll
    for (int p = 0; p < 16; ++p) {
        int c = p * 256 + t;               // 0..4095
        int n = c >> 5, fo = (c & 31) * 4;
        f32x4v v = *(const f32x4v*)(w1 + (size_t)(ng * 128 + n) * 256 + which * 128 + fo);
        half4 h; h[0] = (_Float16)v[0]; h[1] = (_Float16)v[1];
        h[2] = (_Float16)v[2]; h[3] = (_Float16)v[3];
        *(half4*)(wb + n * LDA + fo) = h;
    }
    __syncthreads();

    const int wid = t >> 6;
    const int l = t & 63;
    const int l31 = l & 31, lh = l >> 5;

    f32x16 acc = (f32x16)0.f;
#pragma unroll
    for (int kc = 0; kc < 8; ++kc) {
        half8 af = *(const half8*)(xa + l31 * LDA + kc * 16 + lh * 8);
        half8 bf = *(const half8*)(wb + (wid * 32 + l31) * LDA + kc * 16 + lh * 8);
        acc = __builtin_amdgcn_mfma_f32_32x32x16_f16(af, bf, acc, 0, 0, 0);
    }

    const int n = ng * 128 + wid * 32 + l31;
    float alpha = g1[n] * rsqrtf(v1[n] + EPS);
    if (which == 0) {
        float bias = alpha * b1[n] + be1[n] - m1[n] * alpha;
#pragma unroll
        for (int r = 0; r < 16; ++r) {
            int m = (r & 3) + 8 * (r >> 2) + 4 * lh;
            hxh[(size_t)(rowbase + m) * 512 + n] = (_Float16)(alpha * acc[r] + bias);
        }
    } else {
        // hy in fragment layout (per-b region of 65536 halves; K16=32)
        const int ks = n >> 4, lhh = (n >> 3) & 1, c = n & 7;
#pragma unroll
        for (int r = 0; r < 16; ++r) {
            int m = (r & 3) + 8 * (r >> 2) + 4 * lh;
            int R = rowbase + m;                // global row = b*128 + j
            int bb = R >> 7, j = R & 127;
            int addr = bb * 65536 + ((j >> 5) * 32 + ks) * 512 + lhh * 256 + (j & 31) * 8 + c;
            hyh[addr] = (_Float16)(alpha * acc[r]);
        }
    }
}

// ---------------------------------------------------------------------------
// fused: one block per (b,i). M=128 (all j), 512->256->128->64 MLP with
// 32x32x16 f16 MFMA, then s=sum_j e, out[j]=e[j]·s. 512 threads = 8 waves.
// L2 phase: A and B fragments streamed DIRECTLY from global (pre-swizzled
// fragment layout, coalesced 1KB/wave loads, L2-resident) -- no LDS staging,
// no k-loop barriers. relu(hx+hy) assembled in registers from LDS-broadcast
// hxs. L3/L4 keep proven 0-conflict LDS form; B direct from global fragments.
// LDS 71168 B -> 2 blocks/CU.
// ---------------------------------------------------------------------------
__global__ __launch_bounds__(512, 4)
void fused_kernel(
    const _Float16* __restrict__ hxh, const _Float16* __restrict__ hyh,
    const _Float16* __restrict__ w2h, const _Float16* __restrict__ w3h,
    const _Float16* __restrict__ w4h,
    const float* __restrict__ b2f, const float* __restrict__ b3f,
    const float* __restrict__ b4,
    float* __restrict__ out)
{
    constexpr int LD2 = 264;  // a2 row stride (halves), 528 B (proven 0-conflict)
    constexpr int LD3 = 136;  // a3 row stride (halves), 272 B
    constexpr int LDE = 68;   // es row stride (f32), 272 B

    __shared__ char smem[3584 + 67584] __attribute__((aligned(16)));
    _Float16* hxs = (_Float16*)smem;             // [512] f16   1024 B
    float* spart  = (float*)(smem + 1024);       // [8][64]     2048 B
    float* ss     = (float*)(smem + 3072);       // [64]         256 B
    char* R1 = smem + 3584;
    _Float16* a2  = (_Float16*)R1;               // [128][264] 67584 B (after L2)
    _Float16* a3  = (_Float16*)R1;               // [128][136] (after L3)
    float*    es  = (float*)R1;                  // [128][68]  (after L4)

    const int b = blockIdx.x >> 7;
    const int i = blockIdx.x & 127;
    const int t = threadIdx.x;
    const int wid = t >> 6;
    const int l   = t & 63;
    const int l31 = l & 31;
    const int lh  = l >> 5;

    if (t < 64)
        *(half8*)(hxs + t * 8) = *(const half8*)(hxh + (size_t)(b * 128 + i) * 512 + t * 8);
    __syncthreads();

    const int wm = wid >> 2, wn = wid & 3;       // 2 x 4 wave grid (L2/L3)

    // ---------------- layer 2: [128x512] @ [256x512]^T ----------------
    f32x16 acc2[2][2];
#pragma unroll
    for (int mt = 0; mt < 2; ++mt)
#pragma unroll
        for (int nt = 0; nt < 2; ++nt) acc2[mt][nt] = (f32x16)0.f;

    // fragment base pointers (coalesced: +lane*8)
    const _Float16* paf0 = hyh + (size_t)b * 65536 + (wm * 2) * 32 * 512 + l * 8;
    const _Float16* paf1 = paf0 + 32 * 512;
    const _Float16* pbf0 = w2h + (wn * 2) * 32 * 512 + l * 8;
    const _Float16* pbf1 = pbf0 + 32 * 512;

    auto LD = [&](half8& A0, half8& A1, half8& B0, half8& B1, int ks) {
        A0 = *(const half8*)(paf0 + ks * 512);
        A1 = *(const half8*)(paf1 + ks * 512);
        B0 = *(const half8*)(pbf0 + ks * 512);
        B1 = *(const half8*)(pbf1 + ks * 512);
    };
    auto STEP = [&](half8 A0, half8 A1, half8 B0, half8 B1, int ks) {
        half8 rx = *(const half8*)(hxs + ks * 16 + lh * 8);
        half8 s0 = A0 + rx;
        half8 s1 = A1 + rx;
        half8 af0, af1;
#pragma unroll
        for (int c = 0; c < 8; ++c) {
            af0[c] = s0[c] > (_Float16)0.f ? s0[c] : (_Float16)0.f;
            af1[c] = s1[c] > (_Float16)0.f ? s1[c] : (_Float16)0.f;
        }
        acc2[0][0] = __builtin_amdgcn_mfma_f32_32x32x16_f16(af0, B0, acc2[0][0], 0, 0, 0);
        acc2[1][0] = __builtin_amdgcn_mfma_f32_32x32x16_f16(af1, B0, acc2[1][0], 0, 0, 0);
        acc2[0][1] = __builtin_amdgcn_mfma_f32_32x32x16_f16(af0, B1, acc2[0][1], 0, 0, 0);
        acc2[1][1] = __builtin_amdgcn_mfma_f32_32x32x16_f16(af1, B1, acc2[1][1], 0, 0, 0);
    };

    {
        half8 cA0, cA1, cB0, cB1, nA0, nA1, nB0, nB1;
        LD(cA0, cA1, cB0, cB1, 0);
#pragma unroll 2
        for (int ks = 0; ks < 32; ks += 2) {
            LD(nA0, nA1, nB0, nB1, ks + 1);
            STEP(cA0, cA1, cB0, cB1, ks);
            if (ks + 2 < 32) LD(cA0, cA1, cB0, cB1, ks + 2);
            STEP(nA0, nA1, nB0, nB1, ks + 1);
        }
    }

    // epilogue -> a2 (fp16, relu)
    {
        float bb0 = b2f[wn * 64 + l31];
        float bb1 = b2f[wn * 64 + 32 + l31];
#pragma unroll
        for (int mt = 0; mt < 2; ++mt)
#pragma unroll
            for (int r = 0; r < 16; ++r) {
                int m = wm * 64 + mt * 32 + (r & 3) + 8 * (r >> 2) + 4 * lh;
                a2[m * LD2 + wn * 64 + l31]      = (_Float16)fmaxf(acc2[mt][0][r] + bb0, 0.f);
                a2[m * LD2 + wn * 64 + 32 + l31] = (_Float16)fmaxf(acc2[mt][1][r] + bb1, 0.f);
            }
    }
    __syncthreads();

    // ---------------- layer 3: [128x256] @ [128x256]^T, B = global fragments ----
    f32x16 acc3[2];
    acc3[0] = (f32x16)0.f; acc3[1] = (f32x16)0.f;
#pragma unroll 8
    for (int kc = 0; kc < 16; ++kc) {
        half8 bfr = *(const half8*)(w3h + (wn * 16 + kc) * 512 + l * 8);
        half8 af0 = *(const half8*)(a2 + (wm * 64 + l31) * LD2 + kc * 16 + lh * 8);
        half8 af1 = *(const half8*)(a2 + (wm * 64 + 32 + l31) * LD2 + kc * 16 + lh * 8);
        acc3[0] = __builtin_amdgcn_mfma_f32_32x32x16_f16(af0, bfr, acc3[0], 0, 0, 0);
        acc3[1] = __builtin_amdgcn_mfma_f32_32x32x16_f16(af1, bfr, acc3[1], 0, 0, 0);
    }
    __syncthreads();
    {
        float b3v = b3f[wn * 32 + l31];
#pragma unroll
        for (int mt = 0; mt < 2; ++mt)
#pragma unroll
            for (int r = 0; r < 16; ++r) {
                int m = wm * 64 + mt * 32 + (r & 3) + 8 * (r >> 2) + 4 * lh;
                a3[m * LD3 + wn * 32 + l31] = (_Float16)fmaxf(acc3[mt][r] + b3v, 0.f);
            }
    }
    __syncthreads();

    // ---------------- layer 4: [128x128] @ [64x128]^T, regrid 4x2 ----------
    const int wm4 = wid >> 1, wn4 = wid & 1;
    f32x16 acc4 = (f32x16)0.f;
#pragma unroll
    for (int kc = 0; kc < 8; ++kc) {
        half8 afr = *(const half8*)(a3 + (wm4 * 32 + l31) * LD3 + kc * 16 + lh * 8);
        half8 bfr = *(const half8*)(w4h + (wn4 * 8 + kc) * 512 + l * 8);
        acc4 = __builtin_amdgcn_mfma_f32_32x32x16_f16(afr, bfr, acc4, 0, 0, 0);
    }
    __syncthreads();  // a3 reads done before es overwrites it
    {
        float b4v = b4[wn4 * 32 + l31];
#pragma unroll
        for (int r = 0; r < 16; ++r) {
            int m = wm4 * 32 + (r & 3) + 8 * (r >> 2) + 4 * lh;
            es[m * LDE + wn4 * 32 + l31] = acc4[r] + b4v;
        }
    }
    __syncthreads();

    // ---------------- s = sum_j e ; out[j] = sum_k e[j][k]*s[k] ------------
    {
        float sv = 0.f;
#pragma unroll
        for (int jj = 0; jj < 16; ++jj) sv += es[(wid + jj * 8) * LDE + l];
        spart[wid * 64 + l] = sv;
    }
    __syncthreads();
    if (t < 64) {
        float s2 = 0.f;
#pragma unroll
        for (int r = 0; r < 8; ++r) s2 += spart[r * 64 + t];
        ss[t] = s2;
    }
    __syncthreads();
    {
        const int j = t >> 2, q = t & 3;
        float p = 0.f;
#pragma unroll
        for (int c = 0; c < 16; ++c) {
            int k = q + 4 * c;               // k-interleaved: 2 lanes/bank
            p += es[j * LDE + k] * ss[k];
        }
        p += __shfl_xor(p, 1);
        p += __shfl_xor(p, 2);
        if (q == 0) out[(size_t)(b * 128 + i) * 128 + j] = p;
    }
}

// ---------------------------------------------------------------------------
extern "C" void kernel_launch(void* const* d_in, const int* in_sizes, int n_in,
                              void* d_out, int out_size, void* d_ws, size_t ws_size,
                              hipStream_t stream)
{
    (void)in_sizes; (void)n_in; (void)out_size; (void)ws_size;

    const float* x   = (const float*)d_in[0];
    const float* y   = (const float*)d_in[1];
    const float* w1  = (const float*)d_in[2];
    const float* b1  = (const float*)d_in[3];
    const float* g1  = (const float*)d_in[4];
    const float* be1 = (const float*)d_in[5];
    const float* m1  = (const float*)d_in[6];
    const float* v1  = (const float*)d_in[7];
    const float* w2  = (const float*)d_in[8];
    const float* b2  = (const float*)d_in[9];
    const float* g2  = (const float*)d_in[10];
    const float* be2 = (const float*)d_in[11];
    const float* m2  = (const float*)d_in[12];
    const float* v2  = (const float*)d_in[13];
    const float* w3  = (const float*)d_in[14];
    const float* b3  = (const float*)d_in[15];
    const float* g3  = (const float*)d_in[16];
    const float* be3 = (const float*)d_in[17];
    const float* m3  = (const float*)d_in[18];
    const float* v3  = (const float*)d_in[19];
    const float* w4  = (const float*)d_in[20];
    const float* b4  = (const float*)d_in[21];
    float* out = (float*)d_out;

    // workspace layout (~2.44 MB)
    float* b2f = (float*)d_ws;                 // 256 f32
    float* b3f = b2f + 256;                    // 128 f32
    _Float16* w2h = (_Float16*)(b3f + 128);    // 131072 f16 (fragment layout)
    _Float16* w3h = w2h + 131072;              // 32768 f16  (fragment layout)
    _Float16* w4h = w3h + 32768;               // 8192 f16   (fragment layout)
    _Float16* hxh = w4h + 8192;                // 524288 f16 (linear)
    _Float16* hyh = hxh + 524288;              // 524288 f16 (fragment layout per b)

    hipLaunchKernelGGL(pre_kernel, dim3(320), dim3(256), 0, stream,
                       x, y, w1, b1, g1, be1, m1, v1,
                       w2, b2, g2, be2, m2, v2,
                       w3, b3, g3, be3, m3, v3,
                       w4,
                       hxh, hyh, w2h, w3h, w4h, b2f, b3f);

    hipLaunchKernelGGL(fused_kernel, dim3(1024), dim3(512), 0, stream,
                       hxh, hyh, w2h, w3h, w4h, b2f, b3f, b4, out);
}